// Round 8
// baseline (100.845 us; speedup 1.0000x reference)
//
#include <hip/hip_runtime.h>
#include <hip/hip_bf16.h>

typedef __attribute__((ext_vector_type(8))) short bf16x8;
typedef __attribute__((ext_vector_type(4))) float f32x4;

#define D_DIM 256     // input feature dim
#define H_DIM 128     // hidden dim per branch
#define MAX_RS 25088  // rows per LDS half-range (100352 B f32 accumulator)
#define NSLICE 128    // edge slices (=> 256 blocks, 1 per CU)

// RNE float->bf16 (bit pattern)
__device__ inline ushort f2bf(float f) {
    union { float f; unsigned u; } a; a.f = f;
    unsigned r = a.u + 0x7fffu + ((a.u >> 16) & 1u);
    return (ushort)(r >> 16);
}
__device__ inline float bf2f(unsigned hi16) {
    union { unsigned u; float f; } a; a.u = hi16 << 16;
    return a.f;
}

// K0: build Wt bf16 [hcat][k]; init dis only for fallback path.
__global__ void k0_init(const float* __restrict__ W_nb, const float* __restrict__ W_self,
                        ushort* __restrict__ Wt, float* __restrict__ dis, int N, int init_dis) {
    int i = blockIdx.x * 256 + threadIdx.x;
    if (i < 2 * H_DIM * D_DIM) {
        int sel = i >> 15;
        int r   = i & 32767;
        int k   = r >> 7;
        int h   = r & 127;
        const float* W = sel ? W_self : W_nb;
        Wt[(sel * H_DIM + h) * D_DIM + k] = f2bf(W[k * H_DIM + h]);
    }
    if (init_dis && i < N) dis[i] = 1e-10f;
}

// K1: persistent-B fused GEMM (unchanged from R6).
__global__ __launch_bounds__(512, 2) void k1_gemm(
    const float* __restrict__ x, const ushort* __restrict__ Wt,
    const float* __restrict__ b_nb, const float* __restrict__ b_self,
    const float* __restrict__ W_att,
    float* __restrict__ g_nb, float* __restrict__ g_self, int N, int ntiles)
{
    __shared__ __align__(16) ushort A_lds[64][264];
    __shared__ float part[2][2][64];

    const int t    = threadIdx.x;
    const int lane = t & 63;
    const int w    = t >> 6;
    const int rh   = w >> 2;
    const int cg   = w & 3;
    const int br   = cg >> 1;
    const int ch   = cg & 1;
    const int li   = lane & 15;
    const int grp  = lane >> 4;

    float bias[4], aw[4];
    #pragma unroll
    for (int ni = 0; ni < 4; ni++) {
        int hh = ch * 64 + ni * 16 + li;
        bias[ni] = br ? b_self[hh] : b_nb[hh];
        aw[ni]   = W_att[br * H_DIM + hh];
    }

    bf16x8 Bf[4][8];
    #pragma unroll
    for (int ni = 0; ni < 4; ni++)
        #pragma unroll
        for (int ks = 0; ks < 8; ks++)
            Bf[ni][ks] = *reinterpret_cast<const bf16x8*>(
                Wt + (size_t)(cg * 64 + ni * 16 + li) * D_DIM + ks * 32 + grp * 8);

    const int sr = t >> 3;
    const int sc = t & 7;

    for (int rt = blockIdx.x; rt < ntiles; rt += gridDim.x) {
        const int row0 = rt * 64;

        __syncthreads();
        {
            const int gr = row0 + sr;
            const bool v = gr < N;
            const float4* src = reinterpret_cast<const float4*>(x + (size_t)gr * D_DIM);
            #pragma unroll
            for (int j = 0; j < 8; j++) {
                int c4 = sc + j * 8;
                ushort4 o;
                if (v) {
                    float4 f = src[c4];
                    o.x = f2bf(f.x); o.y = f2bf(f.y); o.z = f2bf(f.z); o.w = f2bf(f.w);
                } else { o.x = 0; o.y = 0; o.z = 0; o.w = 0; }
                *reinterpret_cast<ushort4*>(&A_lds[sr][c4 * 4]) = o;
            }
        }
        __syncthreads();

        f32x4 acc[2][4];
        #pragma unroll
        for (int mi = 0; mi < 2; mi++)
            #pragma unroll
            for (int ni = 0; ni < 4; ni++) acc[mi][ni] = f32x4{0.f, 0.f, 0.f, 0.f};

        #pragma unroll
        for (int ks = 0; ks < 8; ks++) {
            bf16x8 af0 = *reinterpret_cast<const bf16x8*>(&A_lds[rh * 32 + li][ks * 32 + grp * 8]);
            bf16x8 af1 = *reinterpret_cast<const bf16x8*>(&A_lds[rh * 32 + 16 + li][ks * 32 + grp * 8]);
            #pragma unroll
            for (int ni = 0; ni < 4; ni++) {
                acc[0][ni] = __builtin_amdgcn_mfma_f32_16x16x32_bf16(af0, Bf[ni][ks], acc[0][ni], 0, 0, 0);
                acc[1][ni] = __builtin_amdgcn_mfma_f32_16x16x32_bf16(af1, Bf[ni][ks], acc[1][ni], 0, 0, 0);
            }
        }

        float p[2][4];
        #pragma unroll
        for (int mi = 0; mi < 2; mi++)
            #pragma unroll
            for (int r4 = 0; r4 < 4; r4++) p[mi][r4] = 0.f;
        #pragma unroll
        for (int ni = 0; ni < 4; ni++)
            #pragma unroll
            for (int mi = 0; mi < 2; mi++)
                #pragma unroll
                for (int r4 = 0; r4 < 4; r4++) {
                    float y = acc[mi][ni][r4] + bias[ni];
                    y = y > 0.f ? y : 0.f;
                    p[mi][r4] += y * aw[ni];
                }
        #pragma unroll
        for (int mi = 0; mi < 2; mi++)
            #pragma unroll
            for (int r4 = 0; r4 < 4; r4++) {
                float v = p[mi][r4];
                #pragma unroll
                for (int m = 1; m < 16; m <<= 1) v += __shfl_xor(v, m);
                if (li == 0)
                    part[br][ch][rh * 32 + mi * 16 + grp * 4 + r4] = v;
            }
        __syncthreads();

        if (t < 128) {
            int b_ = t >> 6, lr = t & 63;
            int gr = row0 + lr;
            if (gr < N) {
                float val = part[b_][0][lr] + part[b_][1][lr];
                if (b_) g_self[gr] = val; else g_nb[gr] = val;
            }
        }
    }
}

// K2S: fused gate + LDS-privatized rowsum scatter. grid = NSLICE*2 blocks, 512 thr.
// Block (s = bid>>1, g = bid&1): stream edge slice s; compute mv; g==0 writes out;
// ds_add_f32 rows in [g*RS, g*RS+RS); flush bf16 partials to priv[s].
// No global atomics, no scattered global stores.
__global__ __launch_bounds__(512, 1) void k2s_gate_scatter(
    const int* __restrict__ row, const int* __restrict__ col,
    const float* __restrict__ values, const float* __restrict__ noise,
    const float* __restrict__ g_nb, const float* __restrict__ g_self,
    const float* __restrict__ b_att,
    float* __restrict__ out, ushort* __restrict__ priv,
    int E, int ES, int RS, int Npad)
{
    __shared__ float acc[MAX_RS];
    const int s = blockIdx.x >> 1;
    const int g = blockIdx.x & 1;
    const int t = threadIdx.x;

    for (int i = t; i < RS; i += 512) acc[i] = 0.f;
    __syncthreads();

    const float ba = b_att[0];
    const int base = s * ES;
    int end = base + ES; if (end > E) end = E;
    const int lo = g * RS;

    for (int e = base + t; e < end; e += 512) {
        int   r = row[e], c = col[e];
        float v = values[e];
        float u = noise[e] + 1e-7f;
        float la = g_nb[r] + g_self[c] + ba;
        float gate = u / (u + (1.f - u) * __expf(-la));
        float mask = fminf(fmaxf(gate * 1.6f - 0.5f, 0.f), 1.f);
        float m = v * mask;
        if (g == 0) out[e] = m;
        int d = r - lo;
        if ((unsigned)d < (unsigned)RS && m != 0.f)
            atomicAdd(&acc[d], m);
    }
    __syncthreads();

    // flush: 2 rows/thread packed as uint, coalesced
    ushort* dst = priv + (size_t)s * Npad + lo;
    for (int i = t * 2; i < RS; i += 1024) {
        unsigned pk = (unsigned)f2bf(acc[i]) | ((unsigned)f2bf(acc[i + 1]) << 16);
        *reinterpret_cast<unsigned*>(dst + i) = pk;
    }
}

// K2C: dis[n] = rsqrt(1e-10 + sum_s bf16 priv[s][n]); 2 rows/thread, coalesced.
__global__ __launch_bounds__(256) void k2c_reduce(
    const ushort* __restrict__ priv, float* __restrict__ dis, int N, int Npad, int S)
{
    int n0 = (blockIdx.x * 256 + threadIdx.x) * 2;
    if (n0 >= N) return;
    float s0 = 1e-10f, s1 = 1e-10f;
    for (int s = 0; s < S; s++) {
        unsigned v = *reinterpret_cast<const unsigned*>(priv + (size_t)s * Npad + n0);
        s0 += bf2f(v & 0xffffu);
        s1 += bf2f(v >> 16);
    }
    dis[n0] = rsqrtf(s0);
    if (n0 + 1 < N) dis[n0 + 1] = rsqrtf(s1);
}

// Fallback path (N too large for LDS halves): fused gate + global atomic.
__global__ __launch_bounds__(256) void k2_atomic_fb(
    const int* __restrict__ row, const int* __restrict__ col,
    const float* __restrict__ values, const float* __restrict__ noise,
    const float* __restrict__ g_nb, const float* __restrict__ g_self,
    const float* __restrict__ b_att,
    float* __restrict__ out, float* __restrict__ dis, int E)
{
    int e = blockIdx.x * 256 + threadIdx.x;
    if (e >= E) return;
    int   r = row[e], c = col[e];
    float v = values[e];
    float u = noise[e] + 1e-7f;
    float la = g_nb[r] + g_self[c] + b_att[0];
    float gate = u / (u + (1.f - u) * __expf(-la));
    float mask = fminf(fmaxf(gate * 1.6f - 0.5f, 0.f), 1.f);
    float m = v * mask;
    out[e] = m;
    if (m != 0.f) atomicAdd(&dis[r], m);
}
__global__ __launch_bounds__(256) void k2c_rsqrt_fb(float* __restrict__ dis, int N)
{
    int n = blockIdx.x * 256 + threadIdx.x;
    if (n < N) dis[n] = rsqrtf(dis[n]);
}

// K3: symmetric degree normalization, gathers precomputed dis.
__global__ __launch_bounds__(256) void k3_edge2(
    const int* __restrict__ row, const int* __restrict__ col,
    float* __restrict__ out, const float* __restrict__ dis, int E)
{
    int e = blockIdx.x * 256 + threadIdx.x;
    if (e >= E) return;
    out[e] = out[e] * dis[row[e]] * dis[col[e]];
}

extern "C" void kernel_launch(void* const* d_in, const int* in_sizes, int n_in,
                              void* d_out, int out_size, void* d_ws, size_t ws_size,
                              hipStream_t stream) {
    const float* x      = (const float*)d_in[0];
    const float* W_nb   = (const float*)d_in[1];
    const float* b_nb   = (const float*)d_in[2];
    const float* W_self = (const float*)d_in[3];
    const float* b_self = (const float*)d_in[4];
    const float* W_att  = (const float*)d_in[5];
    const float* b_att  = (const float*)d_in[6];
    const float* values = (const float*)d_in[7];
    const float* noise  = (const float*)d_in[8];
    const int*   row    = (const int*)d_in[9];
    const int*   col    = (const int*)d_in[10];

    const int N = in_sizes[0] / D_DIM;
    const int E = in_sizes[7];
    float* out = (float*)d_out;

    const int RS   = (N + 1) / 2;          // rows per half
    const int Npad = 2 * ((RS + 1) & ~1);  // even-aligned total rows in priv

    char* ws = (char*)d_ws;
    ushort* Wt     = (ushort*)ws;                       // 131072 B
    float*  g_nb   = (float*)(ws + 131072);             // N
    float*  g_self = g_nb + N;                          // N
    float*  dis    = g_self + N;                        // N
    ushort* priv   = (ushort*)(dis + N);                // NSLICE * Npad bf16

    size_t need = 131072 + (size_t)3 * N * 4 + (size_t)NSLICE * Npad * 2;
    bool lds_path = (RS <= MAX_RS) && (need <= ws_size);

    int init_n = 2 * H_DIM * D_DIM;
    if (N > init_n) init_n = N;
    k0_init<<<(init_n + 255) / 256, 256, 0, stream>>>(W_nb, W_self, Wt, dis, N, lds_path ? 0 : 1);

    const int ntiles = (N + 63) / 64;
    k1_gemm<<<256, 512, 0, stream>>>(x, Wt, b_nb, b_self, W_att, g_nb, g_self, N, ntiles);

    if (lds_path) {
        const int ES = (E + NSLICE - 1) / NSLICE;
        k2s_gate_scatter<<<NSLICE * 2, 512, 0, stream>>>(row, col, values, noise,
                                                         g_nb, g_self, b_att,
                                                         out, priv, E, ES, RS, Npad);
        k2c_reduce<<<((N + 1) / 2 + 255) / 256, 256, 0, stream>>>(priv, dis, N, Npad, NSLICE);
    } else {
        k2_atomic_fb<<<(E + 255) / 256, 256, 0, stream>>>(row, col, values, noise,
                                                          g_nb, g_self, b_att, out, dis, E);
        k2c_rsqrt_fb<<<(N + 255) / 256, 256, 0, stream>>>(dis, N);
    }

    k3_edge2<<<(E + 255) / 256, 256, 0, stream>>>(row, col, out, dis, E);
}